// Round 4
// baseline (41.824 us; speedup 1.0000x reference)
//
#include <hip/hip_runtime.h>
#include <hip/hip_bf16.h>

#define NPTS 2048      // N == M == 2048
#define QMIX 8
#define LATD 64
#define IT   16        // i-rows per pair block

typedef float v2f __attribute__((ext_vector_type(2)));

__device__ __forceinline__ float softplus_f(float x) {
    return fmaxf(x, 0.0f) + log1pf(expf(-fabsf(x)));
}
__device__ __forceinline__ float selu_f(float z) {
    const float sc = 1.0507009873554805f;   // selu scale
    const float sa = 1.7580993408473766f;   // scale * alpha
    return (z > 0.0f) ? sc * z : sa * expm1f(z);
}

// Coefficient layout, k = 0..7 per (point, q):
//   [EF*A00, EF*A11, EF*A22, 2EF*A01, 2EF*A02, 2EF*A12, w*cos, w*sin]
// with EF = sqrt(5)*log2(e) folded in so the pair kernel's dot gives
// u = EF*r directly (exp(-sqrt5*r) = exp2(-u)).
// FX:  [i][q*8+k]                 (linear, 64 floats per row)
// FYI: [j>>1][ (q*8+k)*2 + (j&1)] (j-pair interleaved, 128 floats per pair)
__global__ __launch_bounds__(640) void feat_kernel(
    const float* __restrict__ xin, const float* __restrict__ yin,
    const float* __restrict__ W1, const float* __restrict__ b1,
    const float* __restrict__ Ww, const float* __restrict__ bw,
    const float* __restrict__ Wf, const float* __restrict__ bf,
    const float* __restrict__ Ws, const float* __restrict__ bs,
    float* __restrict__ FX, float* __restrict__ FYI)
{
    __shared__ float hsh[8][LATD];   // hidden layer per local point
    __shared__ float raw[8][80];     // head outputs per local point
    const int t = threadIdx.x;

    // phase 1: h = selu(W1 @ p + b1), one (point, latent) per thread
    if (t < 512) {
        const int pl = t >> 6, l = t & 63;
        const int g = blockIdx.x * 8 + pl;
        const bool isx = (g < NPTS);
        const float* pts = isx ? (xin + 3 * g) : (yin + 3 * (g - NPTS));
        const float z = fmaf(W1[l * 3 + 0], pts[0],
                        fmaf(W1[l * 3 + 1], pts[1],
                        fmaf(W1[l * 3 + 2], pts[2], b1[l])));
        hsh[pl][l] = selu_f(z);
    }
    __syncthreads();

    // phase 2: one (point, q, head-element) per thread; dot(h, W_row) + bias
    {
        const int pl  = t / 80;
        const int rem = t % 80;
        const int q   = rem / 10;
        const int e   = rem % 10;
        const float* row;
        float acc;
        if (e == 0)      { row = Ww + q * LATD;                 acc = bw[q]; }
        else if (e <= 3) { row = Wf + (q * 3 + (e - 1)) * LATD; acc = bf[q * 3 + (e - 1)]; }
        else             { row = Ws + (q * 6 + (e - 4)) * LATD; acc = bs[q * 6 + (e - 4)]; }
#pragma unroll
        for (int l4 = 0; l4 < LATD / 4; ++l4) {
            const float4 rv = reinterpret_cast<const float4*>(row)[l4];
            const float4 hv = *reinterpret_cast<const float4*>(&hsh[pl][l4 * 4]);
            acc = fmaf(rv.x, hv.x, acc);
            acc = fmaf(rv.y, hv.y, acc);
            acc = fmaf(rv.z, hv.z, acc);
            acc = fmaf(rv.w, hv.w, acc);
        }
        raw[pl][rem] = softplus_f(acc);
    }
    __syncthreads();

    // phase 3: assemble per-(point,q) coefficients
    if (t < 64) {
        const int pl2 = t >> 3, q2 = t & 7;
        const int g2  = blockIdx.x * 8 + pl2;
        const bool isx2 = (g2 < NPTS);
        const float* pts2 = isx2 ? (xin + 3 * g2) : (yin + 3 * (g2 - NPTS));
        const float c0 = pts2[0], c1 = pts2[1], c2 = pts2[2];
        const float* r = raw[pl2] + q2 * 10;
        const float w  = r[0];
        const float f0 = r[1], f1 = r[2], f2 = r[3];
        const float s0 = r[4], s1 = r[5], s2 = r[6];
        const float s3 = r[7], s4 = r[8], s5 = r[9];

        // A = L L^T, L = [[s0,0,0],[s1,s2,0],[s3,s4,s5]]
        const float A00 = s0 * s0;
        const float A11 = fmaf(s1, s1, s2 * s2);
        const float A22 = fmaf(s3, s3, fmaf(s4, s4, s5 * s5));
        const float A01 = s0 * s1;
        const float A02 = s0 * s3;
        const float A12 = fmaf(s1, s3, s2 * s4);
        const float ph  = fmaf(f0, c0, fmaf(f1, c1, f2 * c2));
        float sn, cs;
        sincosf(6.283185307179586477f * ph, &sn, &cs);

        const float EF  = 3.2259751249059600974f;  // sqrt(5) * log2(e)
        const float EF2 = 2.0f * EF;
        const float vals[8] = { EF * A00, EF * A11, EF * A22,
                                EF2 * A01, EF2 * A02, EF2 * A12,
                                w * cs, w * sn };
        if (isx2) {
            float* o = FX + (size_t)g2 * 64 + q2 * 8;
            reinterpret_cast<float4*>(o)[0] = make_float4(vals[0], vals[1], vals[2], vals[3]);
            reinterpret_cast<float4*>(o)[1] = make_float4(vals[4], vals[5], vals[6], vals[7]);
        } else {
            const int pi = g2 - NPTS;
            float* o = FYI + (size_t)(pi >> 1) * 128 + q2 * 16 + (pi & 1);
#pragma unroll
            for (int k = 0; k < 8; ++k) o[k * 2] = vals[k];
        }
    }
}

// Pair kernel: thread owns a j-PAIR (j0 = 2*jp, j1 = 2*jp+1) packed into v2f
// lanes, and iterates IT i-rows whose coefficients sit in a 4 KB LDS tile
// (wave-uniform broadcast reads). All math is packed fp32 (v_pk_*_f32).
__global__ __launch_bounds__(256, 2) void pair_kernel(
    const float* __restrict__ xin, const float* __restrict__ yin,
    const float* __restrict__ FX, const float* __restrict__ FYI,
    float* __restrict__ out)
{
    __shared__ float sFX[IT * 64];   // 4 KB
    const int t  = threadIdx.x;
    const int i0 = blockIdx.y * IT;

    // stage FX tile: IT rows * 64 floats = IT*16 float4
    if (t < IT * 16) {
        reinterpret_cast<float4*>(sFX)[t] =
            reinterpret_cast<const float4*>(FX)[i0 * 16 + t];
    }

    const int jp = blockIdx.x * 256 + t;   // j-pair index
    const int j0 = jp * 2;

    // Y features for the pair -> 64 packed v2f regs (j-interleaved layout)
    v2f fyv[64];
    {
        const float4* fp = reinterpret_cast<const float4*>(FYI + (size_t)jp * 128);
#pragma unroll
        for (int n = 0; n < 32; ++n) {
            const float4 v = fp[n];
            fyv[2 * n + 0] = v2f{v.x, v.y};
            fyv[2 * n + 1] = v2f{v.z, v.w};
        }
    }
    const v2f yc0 = v2f{yin[j0 * 3 + 0], yin[j0 * 3 + 3]};
    const v2f yc1 = v2f{yin[j0 * 3 + 1], yin[j0 * 3 + 4]};
    const v2f yc2 = v2f{yin[j0 * 3 + 2], yin[j0 * 3 + 5]};
    __syncthreads();

    const float P1 = 0.69314718055994530942f;  // ln2      (t = u*ln2)
    const float P2 = 0.16013630893549922444f;  // ln2^2/3

#pragma unroll 4
    for (int ii = 0; ii < IT; ++ii) {
        const int i = i0 + ii;
        const v2f d0 = yc0 - xin[i * 3 + 0];
        const v2f d1 = yc1 - xin[i * 3 + 1];
        const v2f d2 = yc2 - xin[i * 3 + 2];
        const v2f p00 = d0 * d0, p11 = d1 * d1, p22 = d2 * d2;
        const v2f p01 = d0 * d1, p02 = d0 * d2, p12 = d1 * d2;

        v2f acc = v2f{0.f, 0.f};
#pragma unroll
        for (int q = 0; q < QMIX; ++q) {
            const float4 ca = *reinterpret_cast<const float4*>(sFX + ii * 64 + q * 8);
            const float4 cb = *reinterpret_cast<const float4*>(sFX + ii * 64 + q * 8 + 4);
            v2f u;
            u  = (fyv[q * 8 + 0] + ca.x) * p00;
            u += (fyv[q * 8 + 1] + ca.y) * p11;
            u += (fyv[q * 8 + 2] + ca.z) * p22;
            u += (fyv[q * 8 + 3] + ca.w) * p01;
            u += (fyv[q * 8 + 4] + cb.x) * p02;
            u += (fyv[q * 8 + 5] + cb.y) * p12;
            // u = EF*r;  mat = (1 + t + t^2/3) * exp(-t), t = u*ln2
            const v2f poly = u * (u * P2 + P1) + 1.0f;
            const v2f ex = v2f{__builtin_amdgcn_exp2f(-u.x),
                               __builtin_amdgcn_exp2f(-u.y)};
            v2f ct = fyv[q * 8 + 6] * cb.z;
            ct += fyv[q * 8 + 7] * cb.w;
            acc += (poly * ex) * ct;
        }
        *reinterpret_cast<float2*>(out + (size_t)i * NPTS + j0) =
            make_float2(acc.x, acc.y);
    }
}

extern "C" void kernel_launch(void* const* d_in, const int* in_sizes, int n_in,
                              void* d_out, int out_size, void* d_ws, size_t ws_size,
                              hipStream_t stream) {
    const float* x  = (const float*)d_in[0];
    const float* y  = (const float*)d_in[1];
    const float* W1 = (const float*)d_in[2];
    const float* b1 = (const float*)d_in[3];
    const float* Ww = (const float*)d_in[4];
    const float* bw = (const float*)d_in[5];
    const float* Wf = (const float*)d_in[6];
    const float* bf = (const float*)d_in[7];
    const float* Ws = (const float*)d_in[8];
    const float* bs = (const float*)d_in[9];
    float* out = (float*)d_out;

    float* FX  = (float*)d_ws;                      // NPTS * 64 floats (512 KB)
    float* FYI = FX + (size_t)NPTS * 64;            // (NPTS/2) * 128 floats (512 KB)

    // features: 4096 points, 8 per block
    feat_kernel<<<dim3((2 * NPTS) / 8), dim3(640), 0, stream>>>(
        x, y, W1, b1, Ww, bw, Wf, bf, Ws, bs, FX, FYI);

    // pairwise: (4 j-pair-blocks of 256 pairs, 128 i-blocks of IT rows)
    pair_kernel<<<dim3(NPTS / 512, NPTS / IT), dim3(256), 0, stream>>>(
        x, y, FX, FYI, out);
}

// Round 5
// 39.841 us; speedup vs baseline: 1.0498x; 1.0498x over previous
//
#include <hip/hip_runtime.h>
#include <hip/hip_bf16.h>

#define NPTS 2048      // N == M == 2048
#define QMIX 8
#define LATD 64
#define IT   8         // i-rows per pair block
#define JPB  128       // j-pairs per block (256 j columns)

typedef float v2f __attribute__((ext_vector_type(2)));

__device__ __forceinline__ float softplus_f(float x) {
    return fmaxf(x, 0.0f) + log1pf(expf(-fabsf(x)));
}
__device__ __forceinline__ float selu_f(float z) {
    const float sc = 1.0507009873554805f;   // selu scale
    const float sa = 1.7580993408473766f;   // scale * alpha
    return (z > 0.0f) ? sc * z : sa * expm1f(z);
}

// Coefficient layout, k = 0..7 per (point, q):
//   [EF*A00, EF*A11, EF*A22, 2EF*A01, 2EF*A02, 2EF*A12, w*cos, w*sin]
// with EF = sqrt(5)*log2(e) folded in so the pair kernel's dot gives
// u = EF*r directly (exp(-sqrt5*r) = exp2(-u)).
// FX:  [i][q*8+k]                  (linear, 64 floats per row)
// FYI: [j>>1][(q*8+k)*2 + (j&1)]   (j-pair interleaved, 128 floats per pair)
__global__ __launch_bounds__(640) void feat_kernel(
    const float* __restrict__ xin, const float* __restrict__ yin,
    const float* __restrict__ W1, const float* __restrict__ b1,
    const float* __restrict__ Ww, const float* __restrict__ bw,
    const float* __restrict__ Wf, const float* __restrict__ bf,
    const float* __restrict__ Ws, const float* __restrict__ bs,
    float* __restrict__ FX, float* __restrict__ FYI)
{
    __shared__ float hsh[8][LATD];   // hidden layer per local point
    __shared__ float raw[8][80];     // head outputs per local point
    const int t = threadIdx.x;

    // phase 1: h = selu(W1 @ p + b1), one (point, latent) per thread
    if (t < 512) {
        const int pl = t >> 6, l = t & 63;
        const int g = blockIdx.x * 8 + pl;
        const bool isx = (g < NPTS);
        const float* pts = isx ? (xin + 3 * g) : (yin + 3 * (g - NPTS));
        const float z = fmaf(W1[l * 3 + 0], pts[0],
                        fmaf(W1[l * 3 + 1], pts[1],
                        fmaf(W1[l * 3 + 2], pts[2], b1[l])));
        hsh[pl][l] = selu_f(z);
    }
    __syncthreads();

    // phase 2: one (point, q, head-element) per thread; dot(h, W_row) + bias
    {
        const int pl  = t / 80;
        const int rem = t % 80;
        const int q   = rem / 10;
        const int e   = rem % 10;
        const float* row;
        float acc;
        if (e == 0)      { row = Ww + q * LATD;                 acc = bw[q]; }
        else if (e <= 3) { row = Wf + (q * 3 + (e - 1)) * LATD; acc = bf[q * 3 + (e - 1)]; }
        else             { row = Ws + (q * 6 + (e - 4)) * LATD; acc = bs[q * 6 + (e - 4)]; }
#pragma unroll
        for (int l4 = 0; l4 < LATD / 4; ++l4) {
            const float4 rv = reinterpret_cast<const float4*>(row)[l4];
            const float4 hv = *reinterpret_cast<const float4*>(&hsh[pl][l4 * 4]);
            acc = fmaf(rv.x, hv.x, acc);
            acc = fmaf(rv.y, hv.y, acc);
            acc = fmaf(rv.z, hv.z, acc);
            acc = fmaf(rv.w, hv.w, acc);
        }
        raw[pl][rem] = softplus_f(acc);
    }
    __syncthreads();

    // phase 3: assemble per-(point,q) coefficients
    if (t < 64) {
        const int pl2 = t >> 3, q2 = t & 7;
        const int g2  = blockIdx.x * 8 + pl2;
        const bool isx2 = (g2 < NPTS);
        const float* pts2 = isx2 ? (xin + 3 * g2) : (yin + 3 * (g2 - NPTS));
        const float c0 = pts2[0], c1 = pts2[1], c2 = pts2[2];
        const float* r = raw[pl2] + q2 * 10;
        const float w  = r[0];
        const float f0 = r[1], f1 = r[2], f2 = r[3];
        const float s0 = r[4], s1 = r[5], s2 = r[6];
        const float s3 = r[7], s4 = r[8], s5 = r[9];

        // A = L L^T, L = [[s0,0,0],[s1,s2,0],[s3,s4,s5]]
        const float A00 = s0 * s0;
        const float A11 = fmaf(s1, s1, s2 * s2);
        const float A22 = fmaf(s3, s3, fmaf(s4, s4, s5 * s5));
        const float A01 = s0 * s1;
        const float A02 = s0 * s3;
        const float A12 = fmaf(s1, s3, s2 * s4);
        const float ph  = fmaf(f0, c0, fmaf(f1, c1, f2 * c2));
        float sn, cs;
        sincosf(6.283185307179586477f * ph, &sn, &cs);

        const float EF  = 3.2259751249059600974f;  // sqrt(5) * log2(e)
        const float EF2 = 2.0f * EF;
        const float vals[8] = { EF * A00, EF * A11, EF * A22,
                                EF2 * A01, EF2 * A02, EF2 * A12,
                                w * cs, w * sn };
        if (isx2) {
            float* o = FX + (size_t)g2 * 64 + q2 * 8;
            reinterpret_cast<float4*>(o)[0] = make_float4(vals[0], vals[1], vals[2], vals[3]);
            reinterpret_cast<float4*>(o)[1] = make_float4(vals[4], vals[5], vals[6], vals[7]);
        } else {
            const int pi = g2 - NPTS;
            float* o = FYI + (size_t)(pi >> 1) * 128 + q2 * 16 + (pi & 1);
#pragma unroll
            for (int k = 0; k < 8; ++k) o[k * 2] = vals[k];
        }
    }
}

// Pair kernel: block = 4 waves = {q-half qg} x {j-half jh}. Each thread owns a
// j-PAIR (v2f lanes) and 4 of the 8 mixture components; q-halves are merged
// through an 8 KB LDS reduction. X coefficients sit in a 2 KB LDS tile
// (wave-uniform broadcast ds_read_b128). All math is packed fp32.
__global__ __launch_bounds__(256, 4) void pair_kernel(
    const float* __restrict__ xin, const float* __restrict__ yin,
    const float* __restrict__ FX, const float* __restrict__ FYI,
    float* __restrict__ out)
{
    __shared__ float sFX[IT * 64];        // 2 KB
    __shared__ v2f   red[IT][JPB];        // 8 KB
    const int t    = threadIdx.x;
    const int wave = t >> 6;
    const int lane = t & 63;
    const int qg   = wave & 1;            // q-half: 0 -> q0..3, 1 -> q4..7
    const int jh   = wave >> 1;           // j-half of the block
    const int jpl  = jh * 64 + lane;      // local j-pair 0..127
    const int jp   = blockIdx.x * JPB + jpl;
    const int j0   = jp * 2;
    const int i0   = blockIdx.y * IT;

    // stage FX tile: IT rows * 64 floats = IT*16 float4
    if (t < IT * 16) {
        reinterpret_cast<float4*>(sFX)[t] =
            reinterpret_cast<const float4*>(FX)[i0 * 16 + t];
    }

    // Y features for this wave's 4 q's: 32 v2f, loaded directly (no staging)
    v2f fyv[32];
    {
        const float2* fp = reinterpret_cast<const float2*>(
            FYI + (size_t)jp * 128 + qg * 64);
#pragma unroll
        for (int n = 0; n < 32; ++n) {
            const float2 v = fp[n];
            fyv[n] = v2f{v.x, v.y};
        }
    }
    const v2f yc0 = v2f{yin[j0 * 3 + 0], yin[j0 * 3 + 3]};
    const v2f yc1 = v2f{yin[j0 * 3 + 1], yin[j0 * 3 + 4]};
    const v2f yc2 = v2f{yin[j0 * 3 + 2], yin[j0 * 3 + 5]};
    __syncthreads();

    const float P1 = 0.69314718055994530942f;  // ln2       (t = u*ln2)
    const float P2 = 0.16013630893549922444f;  // ln2^2/3

    v2f acc[IT];
#pragma unroll
    for (int ii = 0; ii < IT; ++ii) acc[ii] = v2f{0.f, 0.f};

#pragma unroll
    for (int ii = 0; ii < IT; ++ii) {
        const int i = i0 + ii;
        const v2f d0 = yc0 - xin[i * 3 + 0];
        const v2f d1 = yc1 - xin[i * 3 + 1];
        const v2f d2 = yc2 - xin[i * 3 + 2];
        const v2f p00 = d0 * d0, p11 = d1 * d1, p22 = d2 * d2;
        const v2f p01 = d0 * d1, p02 = d0 * d2, p12 = d1 * d2;

#pragma unroll
        for (int ql = 0; ql < 4; ++ql) {
            const int q = qg * 4 + ql;
            const float4 ca = *reinterpret_cast<const float4*>(sFX + ii * 64 + q * 8);
            const float4 cb = *reinterpret_cast<const float4*>(sFX + ii * 64 + q * 8 + 4);
            v2f u;
            u  = (fyv[ql * 8 + 0] + ca.x) * p00;
            u += (fyv[ql * 8 + 1] + ca.y) * p11;
            u += (fyv[ql * 8 + 2] + ca.z) * p22;
            u += (fyv[ql * 8 + 3] + ca.w) * p01;
            u += (fyv[ql * 8 + 4] + cb.x) * p02;
            u += (fyv[ql * 8 + 5] + cb.y) * p12;
            // u = EF*r;  mat = (1 + t + t^2/3) * exp(-t), t = u*ln2
            const v2f poly = u * (u * P2 + P1) + 1.0f;
            const v2f ex = v2f{__builtin_amdgcn_exp2f(-u.x),
                               __builtin_amdgcn_exp2f(-u.y)};
            v2f ct = fyv[ql * 8 + 6] * cb.z;
            ct += fyv[ql * 8 + 7] * cb.w;
            acc[ii] += (poly * ex) * ct;
        }
    }

    // merge q-halves: qg1 publishes, qg0 adds and stores
    if (qg == 1) {
#pragma unroll
        for (int ii = 0; ii < IT; ++ii) red[ii][jpl] = acc[ii];
    }
    __syncthreads();
    if (qg == 0) {
#pragma unroll
        for (int ii = 0; ii < IT; ++ii) {
            const v2f s = acc[ii] + red[ii][jpl];
            *reinterpret_cast<float2*>(out + (size_t)(i0 + ii) * NPTS + j0) =
                make_float2(s.x, s.y);
        }
    }
}

extern "C" void kernel_launch(void* const* d_in, const int* in_sizes, int n_in,
                              void* d_out, int out_size, void* d_ws, size_t ws_size,
                              hipStream_t stream) {
    const float* x  = (const float*)d_in[0];
    const float* y  = (const float*)d_in[1];
    const float* W1 = (const float*)d_in[2];
    const float* b1 = (const float*)d_in[3];
    const float* Ww = (const float*)d_in[4];
    const float* bw = (const float*)d_in[5];
    const float* Wf = (const float*)d_in[6];
    const float* bf = (const float*)d_in[7];
    const float* Ws = (const float*)d_in[8];
    const float* bs = (const float*)d_in[9];
    float* out = (float*)d_out;

    float* FX  = (float*)d_ws;                      // NPTS * 64 floats (512 KB)
    float* FYI = FX + (size_t)NPTS * 64;            // (NPTS/2) * 128 floats (512 KB)

    // features: 4096 points, 8 per block
    feat_kernel<<<dim3((2 * NPTS) / 8), dim3(640), 0, stream>>>(
        x, y, W1, b1, Ww, bw, Wf, bf, Ws, bs, FX, FYI);

    // pairwise: (8 j-blocks of 256 columns, 256 i-blocks of IT rows)
    pair_kernel<<<dim3(NPTS / (2 * JPB), NPTS / IT), dim3(256), 0, stream>>>(
        x, y, FX, FYI, out);
}

// Round 6
// 31.505 us; speedup vs baseline: 1.3275x; 1.2646x over previous
//
#include <hip/hip_runtime.h>
#include <hip/hip_bf16.h>

#define NPTS 2048      // N == M == 2048
#define QMIX 8
#define LATD 64
#define IT   16        // i-rows per pair block (two half-passes of 8)
#define HIT  8
#define JPB  128       // j-pairs per block (256 j columns)

typedef float v2f __attribute__((ext_vector_type(2)));

__device__ __forceinline__ float softplus_f(float x) {
    return fmaxf(x, 0.0f) + log1pf(expf(-fabsf(x)));
}
__device__ __forceinline__ float selu_f(float z) {
    const float sc = 1.0507009873554805f;   // selu scale
    const float sa = 1.7580993408473766f;   // scale * alpha
    return (z > 0.0f) ? sc * z : sa * expm1f(z);
}

// Coefficient layout, k = 0..7 per (point, q):
//   [EF*A00, EF*A11, EF*A22, 2EF*A01, 2EF*A02, 2EF*A12, w*cos, w*sin]
// with EF = sqrt(5)*log2(e) folded in (u = EF*r; exp(-sqrt5 r) = exp2(-u)).
// FX:  [i][q*8+k]                  (linear, 64 floats per row)
// FYI: [j>>1][(q*8+k)*2 + (j&1)]   (j-pair interleaved, 128 floats per pair)
__global__ __launch_bounds__(640) void feat_kernel(
    const float* __restrict__ xin, const float* __restrict__ yin,
    const float* __restrict__ W1, const float* __restrict__ b1,
    const float* __restrict__ Ww, const float* __restrict__ bw,
    const float* __restrict__ Wf, const float* __restrict__ bf,
    const float* __restrict__ Ws, const float* __restrict__ bs,
    float* __restrict__ FX, float* __restrict__ FYI)
{
    __shared__ float hsh[8][LATD + 4];   // padded: conflict-free per-lane reads
    __shared__ float raw[8][80];         // head outputs per local point
    const int t = threadIdx.x;

    // phase 1: h = selu(W1 @ p + b1); t -> (l = t>>3, pl = t&7)
    if (t < 512) {
        const int pl = t & 7, l = t >> 3;
        const int g = blockIdx.x * 8 + pl;
        const bool isx = (g < NPTS);
        const float* pts = isx ? (xin + 3 * g) : (yin + 3 * (g - NPTS));
        const float z = fmaf(W1[l * 3 + 0], pts[0],
                        fmaf(W1[l * 3 + 1], pts[1],
                        fmaf(W1[l * 3 + 2], pts[2], b1[l])));
        hsh[pl][l] = selu_f(z);
    }
    __syncthreads();

    // phase 2: t -> (o = t>>3, pl = t&7); o = q*10 + e.
    // A wave spans 8 o-values x 8 points: only 8 distinct weight rows per
    // wave-load (coalesced-ish), hsh reads per-lane conflict-free (padded).
    {
        const int o  = t >> 3;
        const int pl = t & 7;
        const int q  = o / 10;
        const int e  = o % 10;
        const float* row;
        float acc;
        if (e == 0)      { row = Ww + q * LATD;                 acc = bw[q]; }
        else if (e <= 3) { row = Wf + (q * 3 + (e - 1)) * LATD; acc = bf[q * 3 + (e - 1)]; }
        else             { row = Ws + (q * 6 + (e - 4)) * LATD; acc = bs[q * 6 + (e - 4)]; }
#pragma unroll
        for (int l4 = 0; l4 < LATD / 4; ++l4) {
            const float4 rv = reinterpret_cast<const float4*>(row)[l4];
            const float4 hv = *reinterpret_cast<const float4*>(&hsh[pl][l4 * 4]);
            acc = fmaf(rv.x, hv.x, acc);
            acc = fmaf(rv.y, hv.y, acc);
            acc = fmaf(rv.z, hv.z, acc);
            acc = fmaf(rv.w, hv.w, acc);
        }
        raw[pl][o] = softplus_f(acc);
    }
    __syncthreads();

    // phase 3: assemble per-(point,q) coefficients
    if (t < 64) {
        const int pl2 = t >> 3, q2 = t & 7;
        const int g2  = blockIdx.x * 8 + pl2;
        const bool isx2 = (g2 < NPTS);
        const float* pts2 = isx2 ? (xin + 3 * g2) : (yin + 3 * (g2 - NPTS));
        const float c0 = pts2[0], c1 = pts2[1], c2 = pts2[2];
        const float* r = raw[pl2] + q2 * 10;
        const float w  = r[0];
        const float f0 = r[1], f1 = r[2], f2 = r[3];
        const float s0 = r[4], s1 = r[5], s2 = r[6];
        const float s3 = r[7], s4 = r[8], s5 = r[9];

        // A = L L^T, L = [[s0,0,0],[s1,s2,0],[s3,s4,s5]]
        const float A00 = s0 * s0;
        const float A11 = fmaf(s1, s1, s2 * s2);
        const float A22 = fmaf(s3, s3, fmaf(s4, s4, s5 * s5));
        const float A01 = s0 * s1;
        const float A02 = s0 * s3;
        const float A12 = fmaf(s1, s3, s2 * s4);
        const float ph  = fmaf(f0, c0, fmaf(f1, c1, f2 * c2));
        float sn, cs;
        sincosf(6.283185307179586477f * ph, &sn, &cs);

        const float EF  = 3.2259751249059600974f;  // sqrt(5) * log2(e)
        const float EF2 = 2.0f * EF;
        const float vals[8] = { EF * A00, EF * A11, EF * A22,
                                EF2 * A01, EF2 * A02, EF2 * A12,
                                w * cs, w * sn };
        if (isx2) {
            float* o = FX + (size_t)g2 * 64 + q2 * 8;
            reinterpret_cast<float4*>(o)[0] = make_float4(vals[0], vals[1], vals[2], vals[3]);
            reinterpret_cast<float4*>(o)[1] = make_float4(vals[4], vals[5], vals[6], vals[7]);
        } else {
            const int pi = g2 - NPTS;
            float* o = FYI + (size_t)(pi >> 1) * 128 + q2 * 16 + (pi & 1);
#pragma unroll
            for (int k = 0; k < 8; ++k) o[k * 2] = vals[k];
        }
    }
}

// Pair kernel: block = 4 waves = {q-half qg} x {j-half jh}. Thread owns a
// j-PAIR (v2f lanes) and 4 of 8 mixture components. IT=16 i-rows staged in a
// 4 KB LDS tile (wave-uniform broadcast ds_read_b128), processed as two
// half-passes of 8 rows so acc stays at 16 VGPR. q-halves merged via an
// 8 KB LDS reduction per half-pass.
__global__ __launch_bounds__(256, 4) void pair_kernel(
    const float* __restrict__ xin, const float* __restrict__ yin,
    const float* __restrict__ FX, const float* __restrict__ FYI,
    float* __restrict__ out)
{
    __shared__ float sFX[IT * 64];        // 4 KB
    __shared__ v2f   red[HIT][JPB];       // 8 KB
    const int t    = threadIdx.x;
    const int wave = t >> 6;
    const int lane = t & 63;
    const int qg   = wave & 1;            // q-half: 0 -> q0..3, 1 -> q4..7
    const int jh   = wave >> 1;           // j-half of the block
    const int jpl  = jh * 64 + lane;      // local j-pair 0..127
    const int jp   = blockIdx.x * JPB + jpl;
    const int j0   = jp * 2;
    const int i0   = blockIdx.y * IT;

    // stage FX tile: IT rows * 64 floats = 256 float4, one per thread
    reinterpret_cast<float4*>(sFX)[t] =
        reinterpret_cast<const float4*>(FX)[i0 * 16 + t];

    // Y features for this wave's 4 q's: 16 float4 -> 32 v2f regs
    v2f fyv[32];
    {
        const float4* fp = reinterpret_cast<const float4*>(
            FYI + (size_t)jp * 128 + qg * 64);
#pragma unroll
        for (int n = 0; n < 16; ++n) {
            const float4 v = fp[n];
            fyv[2 * n + 0] = v2f{v.x, v.y};
            fyv[2 * n + 1] = v2f{v.z, v.w};
        }
    }
    const v2f yc0 = v2f{yin[j0 * 3 + 0], yin[j0 * 3 + 3]};
    const v2f yc1 = v2f{yin[j0 * 3 + 1], yin[j0 * 3 + 4]};
    const v2f yc2 = v2f{yin[j0 * 3 + 2], yin[j0 * 3 + 5]};
    __syncthreads();

    const float P1 = 0.69314718055994530942f;  // ln2       (t = u*ln2)
    const float P2 = 0.16013630893549922444f;  // ln2^2/3

#pragma unroll
    for (int half = 0; half < 2; ++half) {
        v2f acc[HIT];
#pragma unroll
        for (int k = 0; k < HIT; ++k) acc[k] = v2f{0.f, 0.f};

#pragma unroll
        for (int i2 = 0; i2 < HIT; ++i2) {
            const int ii = half * HIT + i2;
            const int i  = i0 + ii;
            const v2f d0 = yc0 - xin[i * 3 + 0];
            const v2f d1 = yc1 - xin[i * 3 + 1];
            const v2f d2 = yc2 - xin[i * 3 + 2];
            const v2f p00 = d0 * d0, p11 = d1 * d1, p22 = d2 * d2;
            const v2f p01 = d0 * d1, p02 = d0 * d2, p12 = d1 * d2;

#pragma unroll
            for (int ql = 0; ql < 4; ++ql) {
                const int q = qg * 4 + ql;
                const float4 ca = *reinterpret_cast<const float4*>(sFX + ii * 64 + q * 8);
                const float4 cb = *reinterpret_cast<const float4*>(sFX + ii * 64 + q * 8 + 4);
                v2f u;
                u  = (fyv[ql * 8 + 0] + ca.x) * p00;
                u += (fyv[ql * 8 + 1] + ca.y) * p11;
                u += (fyv[ql * 8 + 2] + ca.z) * p22;
                u += (fyv[ql * 8 + 3] + ca.w) * p01;
                u += (fyv[ql * 8 + 4] + cb.x) * p02;
                u += (fyv[ql * 8 + 5] + cb.y) * p12;
                // u = EF*r;  mat = (1 + t + t^2/3) * exp(-t), t = u*ln2
                const v2f poly = u * (u * P2 + P1) + 1.0f;
                const v2f ex = v2f{__builtin_amdgcn_exp2f(-u.x),
                                   __builtin_amdgcn_exp2f(-u.y)};
                v2f ct = fyv[ql * 8 + 6] * cb.z;
                ct += fyv[ql * 8 + 7] * cb.w;
                acc[i2] += (poly * ex) * ct;
            }
        }

        // merge q-halves for this half-pass: qg1 publishes, qg0 adds + stores
        if (qg == 1) {
#pragma unroll
            for (int i2 = 0; i2 < HIT; ++i2) red[i2][jpl] = acc[i2];
        }
        __syncthreads();
        if (qg == 0) {
#pragma unroll
            for (int i2 = 0; i2 < HIT; ++i2) {
                const v2f s = acc[i2] + red[i2][jpl];
                *reinterpret_cast<float2*>(
                    out + (size_t)(i0 + half * HIT + i2) * NPTS + j0) =
                    make_float2(s.x, s.y);
            }
        }
        __syncthreads();   // red reused by next half-pass
    }
}

extern "C" void kernel_launch(void* const* d_in, const int* in_sizes, int n_in,
                              void* d_out, int out_size, void* d_ws, size_t ws_size,
                              hipStream_t stream) {
    const float* x  = (const float*)d_in[0];
    const float* y  = (const float*)d_in[1];
    const float* W1 = (const float*)d_in[2];
    const float* b1 = (const float*)d_in[3];
    const float* Ww = (const float*)d_in[4];
    const float* bw = (const float*)d_in[5];
    const float* Wf = (const float*)d_in[6];
    const float* bf = (const float*)d_in[7];
    const float* Ws = (const float*)d_in[8];
    const float* bs = (const float*)d_in[9];
    float* out = (float*)d_out;

    float* FX  = (float*)d_ws;                      // NPTS * 64 floats (512 KB)
    float* FYI = FX + (size_t)NPTS * 64;            // (NPTS/2) * 128 floats (512 KB)

    // features: 4096 points, 8 per block
    feat_kernel<<<dim3((2 * NPTS) / 8), dim3(640), 0, stream>>>(
        x, y, W1, b1, Ww, bw, Wf, bf, Ws, bs, FX, FYI);

    // pairwise: (8 j-blocks of 256 columns, 128 i-blocks of 16 rows)
    pair_kernel<<<dim3(NPTS / (2 * JPB), NPTS / IT), dim3(256), 0, stream>>>(
        x, y, FX, FYI, out);
}